// Round 5
// baseline (27.595 us; speedup 1.0000x reference)
//
#include <hip/hip_runtime.h>

// Problem constants (match reference)
constexpr int B = 8;
constexpr int T = 4096;
constexpr int D = 768;          // 768 floats = 192 float4
constexpr int W = 2048;
constexpr int MAXW = 8;
constexpr int ROWS_PER_BLOCK = 4;   // one wave per output row
constexpr int NXCD = 8;

// Native clang vector type (required by __builtin_nontemporal_store).
typedef float f32x4 __attribute__((ext_vector_type(4)));

// Block = 256 threads = 4 waves; wave w handles output row blk*4 + w.
// Column-split variant: 3 passes over the 192-float4 row, each pass loads
// 8 source rows' 1KB segment (8 loads in flight, 32 VGPR), accumulates with
// inv-folded 0/inv weights, NT-stores. Live VGPR ~56-64 -> 32 waves/CU
// (vs ~128 VGPR / 16 waves/CU for the all-upfront variant).
__global__ __launch_bounds__(256) void window_mean_kernel(
    const float* __restrict__ features,   // [B, T, D]
    const int*   __restrict__ begins,     // [B, W]
    const int*   __restrict__ ends,       // [B, W]
    float*       __restrict__ out)        // [B, W, D]
{
    // XCD-aware swizzle: grid = 4096 = 8 XCDs * 512 blocks; each XCD gets one
    // contiguous 512-block chunk = exactly one batch (12.6 MB feature slice).
    const int cpx = gridDim.x / NXCD;           // 512
    const int blk = (blockIdx.x % NXCD) * cpx + blockIdx.x / NXCD;

    const int wave = threadIdx.x >> 6;          // 0..3
    const int lane = threadIdx.x & 63;          // 0..63

    // row is wave-uniform; readfirstlane lets begins/ends become s_loads.
    const int row = __builtin_amdgcn_readfirstlane(blk * ROWS_PER_BLOCK + wave);
    const int b   = row >> 11;                  // W = 2048 = 2^11

    const int beg = begins[row];
    int len = ends[row] - beg;                  // guaranteed 1..8
    if (len > MAXW) len = MAXW;
    const float inv = 1.0f / (float)((len < 1) ? 1 : len);

    // Fold 1/cnt into the per-row weights: acc = sum_i v_i * w_i directly.
    float wgt[MAXW];
#pragma unroll
    for (int i = 0; i < MAXW; ++i) wgt[i] = (i < len) ? inv : 0.0f;

    const f32x4* base = reinterpret_cast<const f32x4*>(
        features + ((size_t)b * T + (size_t)beg) * D);
    f32x4* o = reinterpret_cast<f32x4*>(out + (size_t)row * D);

    // begins < T-8 by construction -> all 8 candidate rows in-bounds:
    // load unconditionally, weight with 0 beyond len.
#pragma unroll
    for (int c = 0; c < 3; ++c) {
        f32x4 v[MAXW];
#pragma unroll
        for (int i = 0; i < MAXW; ++i)
            v[i] = base[(size_t)i * (D / 4) + c * 64 + lane];

        f32x4 acc = (f32x4)(0.f);
#pragma unroll
        for (int i = 0; i < MAXW; ++i)
            acc += v[i] * wgt[i];

        // NT store: don't let 50 MB of output evict the gather working set
        // from the 4 MB/XCD L2s.
        __builtin_nontemporal_store(acc, &o[c * 64 + lane]);
    }
}

extern "C" void kernel_launch(void* const* d_in, const int* in_sizes, int n_in,
                              void* d_out, int out_size, void* d_ws, size_t ws_size,
                              hipStream_t stream) {
    const float* features = (const float*)d_in[0];
    const int*   begins   = (const int*)d_in[1];
    const int*   ends     = (const int*)d_in[2];
    float*       out      = (float*)d_out;

    dim3 grid((B * W) / ROWS_PER_BLOCK);   // 4096
    dim3 block(256);
    window_mean_kernel<<<grid, block, 0, stream>>>(features, begins, ends, out);
}